// Round 3
// baseline (662.646 us; speedup 1.0000x reference)
//
#include <hip/hip_runtime.h>
#include <hip/hip_bf16.h>

typedef unsigned short ushort_t;
typedef __attribute__((ext_vector_type(8))) short bf16x8;   // 8 bf16 = 4 VGPRs (guide §3)
typedef __attribute__((ext_vector_type(4))) float f32x4;

#define NBS 256   // scene blocks: 4096 tiles / 256 = 16 each
#define NBV 32    // view blocks:  64 tiles / 32 = 2 each
#define SLDS 264  // LDS row stride in bf16 (256 + 8 pad -> 2-way-only conflicts)

// ws layout (floats): [0,512) xr | [512,1040) S/O accum | [1040,1552) x_skip | [1552,2064) xn
#define WS_XR    0
#define WS_ACC   512
#define WS_SKIP  1040
#define WS_XN    1552

__device__ __forceinline__ float bf2f(ushort_t u) {
    union { unsigned int i; float f; } v; v.i = ((unsigned int)u) << 16; return v.f;
}
__device__ __forceinline__ ushort_t f2bf(float f) {
    union { float f; unsigned int i; } v; v.f = f;
    unsigned int x = v.i;
    return (ushort_t)((x + 0x7fffu + ((x >> 16) & 1u)) >> 16);   // RNE
}
// runtime-flag scalar load (small kernels)
__device__ __forceinline__ float ldr(const void* p, int i, bool f32) {
    return f32 ? ((const float*)p)[i] : bf2f(((const ushort_t*)p)[i]);
}
// detection: g2v_ln_s == ones. bf16 ones -> ushort[0]=0x3F80; fp32 ones -> ushort[0]=0x0000.
__device__ __forceinline__ bool is_bf16(const void* det) {
    return ((const ushort_t*)det)[0] == 0x3F80u;
}

// ---------------------------------------------------------------------------
// Target-node features: xr = ((relu(LN(prev)) @ W + b) @ Wr + br) -> ws (fp32)
// block 0 = view branch, block 1 = scene branch. Also zeroes S/O accumulators.
// ---------------------------------------------------------------------------
__global__ __launch_bounds__(256)
void prep_k(const void* __restrict__ prev,
            const void* __restrict__ lns_v, const void* __restrict__ lnb_v,
            const void* __restrict__ W_v,   const void* __restrict__ b_v,
            const void* __restrict__ Wr_v,  const void* __restrict__ br_v,
            const void* __restrict__ lns_s, const void* __restrict__ lnb_s,
            const void* __restrict__ W_s,   const void* __restrict__ b_s,
            const void* __restrict__ Wr_s,  const void* __restrict__ br_s,
            float* __restrict__ xr, float* __restrict__ accSO)
{
    const bool f32 = !is_bf16(lns_v);
    const int br = blockIdx.x;
    const void* lns = br ? lns_s : lns_v;
    const void* lnb = br ? lnb_s : lnb_v;
    const void* W   = br ? W_s   : W_v;
    const void* bb  = br ? b_s   : b_v;
    const void* Wr  = br ? Wr_s  : Wr_v;
    const void* brr = br ? br_s  : br_v;
    const int t = threadIdx.x;
    for (int i = t; i < 264; i += 256) accSO[br*264 + i] = 0.f;

    __shared__ float g[512];
    __shared__ float xt[256];
    __shared__ float red[8];
    __shared__ float stats[2];
    float a0 = ldr(prev, t, f32), a1 = ldr(prev, t + 256, f32);
    float s1 = a0 + a1, s2 = a0*a0 + a1*a1;
#pragma unroll
    for (int s = 1; s < 64; s <<= 1) { s1 += __shfl_xor(s1, s); s2 += __shfl_xor(s2, s); }
    if ((t & 63) == 0) { red[t >> 6] = s1; red[4 + (t >> 6)] = s2; }
    __syncthreads();
    if (t == 0) {
        float a = 0.f, q = 0.f;
        for (int i = 0; i < 4; i++) { a += red[i]; q += red[4 + i]; }
        float mean = a / 512.f;
        stats[0] = mean;
        stats[1] = rsqrtf(q / 512.f - mean*mean + 1e-5f);
    }
    __syncthreads();
    float mean = stats[0], rstd = stats[1];
    g[t]       = fmaxf((a0 - mean)*rstd*ldr(lns, t, f32)       + ldr(lnb, t, f32), 0.f);
    g[t + 256] = fmaxf((a1 - mean)*rstd*ldr(lns, t + 256, f32) + ldr(lnb, t + 256, f32), 0.f);
    __syncthreads();
    float acc = 0.f;
    for (int i = 0; i < 512; i++) acc += g[i] * ldr(W, i*256 + t, f32);
    xt[t] = acc + ldr(bb, t, f32);
    __syncthreads();
    float acc2 = 0.f;
    for (int j = 0; j < 256; j++) acc2 += xt[j] * ldr(Wr, j*256 + t, f32);
    xr[br*256 + t] = acc2 + ldr(brr, t, f32);
}

// ---------------------------------------------------------------------------
// Main fused GAT, templated on input dtype; the instantiation whose dtype
// doesn't match the detected one exits immediately (both are launched).
// xl = x@Wl + bl (bf16 MFMA; fp32 inputs RNE-converted during LDS staging),
// logits = leaky_relu(xl+xr)·att, UNNORMALIZED exp-sum per block merged via
// device-scope atomicAdd. One wave == one head.
// ---------------------------------------------------------------------------
template<bool F32>
__global__ __launch_bounds__(512, 2)
void gat_k(const void* __restrict__ view_x, const void* __restrict__ scene_x,
           const void* __restrict__ v_Wl, const void* __restrict__ s_Wl,
           const float* __restrict__ xr_all,
           const void* __restrict__ v_bl, const void* __restrict__ s_bl,
           const void* __restrict__ v_att, const void* __restrict__ s_att,
           const void* __restrict__ det,
           float* __restrict__ accSO)
{
    if (is_bf16(det) == F32) return;     // dtype mismatch -> dormant instantiation

    const int tid = threadIdx.x;
    const int wave = tid >> 6;          // == head (8 waves, H=8)
    const int lane = tid & 63;
    const int quad = lane >> 4;
    const int li   = lane & 15;

    const int bid = blockIdx.x;
    const bool scene = bid < NBS;
    const void* xsrc = scene ? scene_x : view_x;
    const void* Wl   = scene ? s_Wl : v_Wl;
    const float* xrp = xr_all + (scene ? 256 : 0);
    const void* blp  = scene ? s_bl  : v_bl;
    const void* attp = scene ? s_att : v_att;
    float* accR      = accSO + (scene ? 264 : 0);
    const int ntiles = scene ? 4096 : 64;
    const int nb     = scene ? NBS : NBV;
    const int slot   = scene ? bid : (bid - NBS);

    // B fragments: frag(nt,k)[j] = Wl[k*32 + quad*8 + j][wave*32 + nt*16 + li]
    bf16x8 Bf[2][8];
#pragma unroll
    for (int nt = 0; nt < 2; nt++)
#pragma unroll
        for (int k = 0; k < 8; k++) {
            union { ushort_t u[8]; bf16x8 v; } tmp;
#pragma unroll
            for (int j = 0; j < 8; j++) {
                int idx = (k*32 + quad*8 + j)*256 + (wave*32 + nt*16 + li);
                tmp.u[j] = F32 ? f2bf(((const float*)Wl)[idx]) : ((const ushort_t*)Wl)[idx];
            }
            Bf[nt][k] = tmp.v;
        }

    const int c0 = wave*32 + li;
    const float xr0 = xrp[c0],           xr1 = xrp[c0 + 16];
    const float at0 = ldr(attp, c0, F32), at1 = ldr(attp, c0 + 16, F32);
    const float bl0 = ldr(blp, c0, F32),  bl1 = ldr(blp, c0 + 16, F32);

    float Ssum = 0.f, oa0 = 0.f, oa1 = 0.f;

    __shared__ __align__(16) ushort_t alds[64 * SLDS];  // 33 KB, 64-row A tile (bf16)

    // staging load of one (row, 8-col chunk) as 8 bf16 packed in int4
    auto stage = [&](int tile, int i) -> int4 {
        int f = tid + 512*i;
        int row = f >> 5, c8 = f & 31;
        size_t base = (size_t)(tile*64 + row)*256 + c8*8;
        if (F32) {
            const float* p = (const float*)xsrc + base;
            float4 a = *(const float4*)p, b = *(const float4*)(p + 4);
            union { ushort_t u[8]; int4 v; } t_;
            t_.u[0]=f2bf(a.x); t_.u[1]=f2bf(a.y); t_.u[2]=f2bf(a.z); t_.u[3]=f2bf(a.w);
            t_.u[4]=f2bf(b.x); t_.u[5]=f2bf(b.y); t_.u[6]=f2bf(b.z); t_.u[7]=f2bf(b.w);
            return t_.v;
        }
        return *(const int4*)((const ushort_t*)xsrc + base);
    };

    int4 pf[4];
#pragma unroll
    for (int i = 0; i < 4; i++) pf[i] = stage(slot, i);

    for (int t = slot; t < ntiles; t += nb) {
        __syncthreads();                 // LDS free from previous iter's readers
#pragma unroll
        for (int i = 0; i < 4; i++) {
            int f = tid + 512*i;
            int row = f >> 5, c8 = f & 31;
            *(int4*)(alds + row*SLDS + c8*8) = pf[i];
        }
        __syncthreads();
        int tn = t + nb;
        if (tn < ntiles) {               // prefetch next tile, overlaps compute
#pragma unroll
            for (int i = 0; i < 4; i++) pf[i] = stage(tn, i);
        }

        f32x4 acc[4][2] = {};            // 4 m-tiles x 2 n-tiles
#pragma unroll
        for (int k = 0; k < 8; k++) {
            bf16x8 a[4];
#pragma unroll
            for (int m = 0; m < 4; m++)
                a[m] = *(const bf16x8*)(alds + (m*16 + li)*SLDS + k*32 + quad*8);
#pragma unroll
            for (int m = 0; m < 4; m++) {
                acc[m][0] = __builtin_amdgcn_mfma_f32_16x16x32_bf16(a[m], Bf[0][k], acc[m][0], 0, 0, 0);
                acc[m][1] = __builtin_amdgcn_mfma_f32_16x16x32_bf16(a[m], Bf[1][k], acc[m][1], 0, 0, 0);
            }
        }

        // epilogue: C/D layout col=lane&15, row=quad*4+reg (guide §3, m89-verified)
#pragma unroll
        for (int m = 0; m < 4; m++) {
#pragma unroll
            for (int r = 0; r < 4; r++) {
                float x0 = acc[m][0][r] + bl0;       // xl at (row, col li)
                float x1 = acc[m][1][r] + bl1;       // xl at (row, col li+16)
                float e0 = x0 + xr0; e0 = e0 > 0.f ? e0 : 0.2f*e0;
                float e1 = x1 + xr1; e1 = e1 > 0.f ? e1 : 0.2f*e1;
                float p = at0*e0 + at1*e1;
                p += __shfl_xor(p, 1);   // reduce over the 16 lanes of the quad
                p += __shfl_xor(p, 2);
                p += __shfl_xor(p, 4);
                p += __shfl_xor(p, 8);
                float w = __expf(fminf(p, 60.f));
                Ssum += w;               // quad-uniform row weight
                oa0 += w * x0;
                oa1 += w * x1;
            }
        }
    }

    // combine quads (each quad saw a disjoint set of rows; li is the column)
    Ssum += __shfl_xor(Ssum, 16); Ssum += __shfl_xor(Ssum, 32);
    oa0  += __shfl_xor(oa0, 16);  oa0  += __shfl_xor(oa0, 32);
    oa1  += __shfl_xor(oa1, 16);  oa1  += __shfl_xor(oa1, 32);

    if (lane == 0) atomicAdd(&accR[wave], Ssum);
    if (lane < 16) {
        atomicAdd(&accR[8 + wave*32 + lane],      oa0);
        atomicAdd(&accR[8 + wave*32 + 16 + lane], oa1);
    }
}

// ---------------------------------------------------------------------------
// out_gat[c] = O[c]/S[h] + bias; x = prev + out_gat; LN + relu -> xn; keep x_skip
// ---------------------------------------------------------------------------
__global__ __launch_bounds__(512)
void combine_k(const float* __restrict__ accSO,
               const void* __restrict__ prev,
               const void* __restrict__ v_bias, const void* __restrict__ s_bias,
               const void* __restrict__ pre_s, const void* __restrict__ pre_b,
               const void* __restrict__ det,
               float* __restrict__ x_skip, float* __restrict__ xn)
{
    const bool f32 = !is_bf16(det);
    const int t = threadIdx.x;
    const int branch = t >> 8, c = t & 255, h = c >> 5;
    float S = accSO[branch*264 + h];
    float o = accSO[branch*264 + 8 + c];
    const void* bias = branch ? s_bias : v_bias;
    float xv = ldr(prev, t, f32) + o / S + ldr(bias, c, f32);
    x_skip[t] = xv;
    __shared__ float red[16];
    __shared__ float stats[2];
    float s1 = xv, s2 = xv*xv;
#pragma unroll
    for (int s = 1; s < 64; s <<= 1) { s1 += __shfl_xor(s1, s); s2 += __shfl_xor(s2, s); }
    if ((t & 63) == 0) { red[t >> 6] = s1; red[8 + (t >> 6)] = s2; }
    __syncthreads();
    if (t == 0) {
        float a = 0.f, q = 0.f;
        for (int i = 0; i < 8; i++) { a += red[i]; q += red[8 + i]; }
        float mean = a / 512.f;
        stats[0] = mean;
        stats[1] = rsqrtf(q / 512.f - mean*mean + 1e-5f);
    }
    __syncthreads();
    float xnv = (xv - stats[0]) * stats[1] * ldr(pre_s, t, f32) + ldr(pre_b, t, f32);
    xn[t] = fmaxf(xnv, 0.f);
}

// ---------------------------------------------------------------------------
// out = x_skip + xn @ mlp_W + mlp_b   (8 blocks x 64 cols); output dtype = input flavor
// ---------------------------------------------------------------------------
__global__ __launch_bounds__(64)
void mlp_k(const float* __restrict__ x_skip, const float* __restrict__ xn,
           const void* __restrict__ W, const void* __restrict__ mb,
           const void* __restrict__ det,
           void* __restrict__ out)
{
    const bool f32 = !is_bf16(det);
    __shared__ float xs[512];
    const int t = threadIdx.x;
    const int col = blockIdx.x*64 + t;
    for (int i = t; i < 512; i += 64) xs[i] = xn[i];
    __syncthreads();
    float acc = 0.f;
    for (int i = 0; i < 512; i++) acc += xs[i] * ldr(W, i*512 + col, f32);
    float r = x_skip[col] + acc + ldr(mb, col, f32);
    if (f32) ((float*)out)[col] = r;
    else     ((ushort_t*)out)[col] = f2bf(r);
}

extern "C" void kernel_launch(void* const* d_in, const int* in_sizes, int n_in,
                              void* d_out, int out_size, void* d_ws, size_t ws_size,
                              hipStream_t stream)
{
    const void* view_x  = d_in[0];
    const void* scene_x = d_in[1];
    const void* prev    = d_in[2];
    const void* g2v_lns = d_in[3];   // ones(512) -> dtype detector
    const void* g2v_lnb = d_in[4];
    const void* g2v_W   = d_in[5];
    const void* g2v_b   = d_in[6];
    const void* g2s_lns = d_in[7];
    const void* g2s_lnb = d_in[8];
    const void* g2s_W   = d_in[9];
    const void* g2s_b   = d_in[10];
    const void* v_Wl    = d_in[11];
    const void* v_bl    = d_in[12];
    const void* v_Wr    = d_in[13];
    const void* v_br    = d_in[14];
    const void* v_att   = d_in[15];
    const void* v_bias  = d_in[16];
    const void* s_Wl    = d_in[17];
    const void* s_bl    = d_in[18];
    const void* s_Wr    = d_in[19];
    const void* s_br    = d_in[20];
    const void* s_att   = d_in[21];
    const void* s_bias  = d_in[22];
    const void* pre_s   = d_in[23];
    const void* pre_b   = d_in[24];
    const void* mlp_W   = d_in[25];
    const void* mlp_b   = d_in[26];

    float* wsf    = (float*)d_ws;
    float* xr     = wsf + WS_XR;
    float* accSO  = wsf + WS_ACC;
    float* x_skip = wsf + WS_SKIP;
    float* xn     = wsf + WS_XN;

    prep_k<<<dim3(2), dim3(256), 0, stream>>>(prev,
                                              g2v_lns, g2v_lnb, g2v_W, g2v_b, v_Wr, v_br,
                                              g2s_lns, g2s_lnb, g2s_W, g2s_b, s_Wr, s_br,
                                              xr, accSO);
    gat_k<false><<<dim3(NBS + NBV), dim3(512), 0, stream>>>(view_x, scene_x, v_Wl, s_Wl, xr,
                                                            v_bl, s_bl, v_att, s_att,
                                                            g2v_lns, accSO);
    gat_k<true><<<dim3(NBS + NBV), dim3(512), 0, stream>>>(view_x, scene_x, v_Wl, s_Wl, xr,
                                                           v_bl, s_bl, v_att, s_att,
                                                           g2v_lns, accSO);
    combine_k<<<dim3(1), dim3(512), 0, stream>>>(accSO, prev, v_bias, s_bias,
                                                 pre_s, pre_b, g2v_lns, x_skip, xn);
    mlp_k<<<dim3(8), dim3(64), 0, stream>>>(x_skip, xn, mlp_W, mlp_b, g2v_lns, d_out);
}

// Round 4
// 604.996 us; speedup vs baseline: 1.0953x; 1.0953x over previous
//
#include <hip/hip_runtime.h>
#include <hip/hip_bf16.h>

typedef unsigned short ushort_t;
typedef __attribute__((ext_vector_type(8))) short bf16x8;   // 8 bf16 = 4 VGPRs (guide §3)
typedef __attribute__((ext_vector_type(4))) float f32x4;

#define NBS 480   // scene blocks (4096 tiles, strided)
#define NBV 32    // view blocks  (64 tiles, 2 each)   -> 512 blocks = 2 blocks/CU
#define SLDS 264  // LDS row stride in bf16 (256 + 8 pad -> 2-way-only conflicts on reads)

// ws layout (floats): [0,512) xr | [512,1040) S/O accum | [1040,1552) x_skip | [1552,2064) xn
#define WS_XR    0
#define WS_ACC   512
#define WS_SKIP  1040
#define WS_XN    1552

__device__ __forceinline__ float bf2f(ushort_t u) {
    union { unsigned int i; float f; } v; v.i = ((unsigned int)u) << 16; return v.f;
}
__device__ __forceinline__ ushort_t f2bf(float f) {
    union { float f; unsigned int i; } v; v.f = f;
    unsigned int x = v.i;
    return (ushort_t)((x + 0x7fffu + ((x >> 16) & 1u)) >> 16);   // RNE
}
__device__ __forceinline__ float ldr(const void* p, int i, bool f32) {
    return f32 ? ((const float*)p)[i] : bf2f(((const ushort_t*)p)[i]);
}
// detection: g2v_ln_s == ones. bf16 ones -> ushort[0]=0x3F80; fp32 ones -> 0x0000.
__device__ __forceinline__ bool is_bf16(const void* det) {
    return ((const ushort_t*)det)[0] == 0x3F80u;
}

// Sum x across each 16-lane DPP row (== our quad group; li = lane&15).
// 4 VALU adds via row_ror DPP -- no LDS, no lgkmcnt stalls (replaces ds_bpermute shfl).
__device__ __forceinline__ float qsum16(float x) {
    union { float f; int i; } a, b;
#define QS_STEP(CTRL) { a.f = x; b.i = __builtin_amdgcn_update_dpp(0, a.i, CTRL, 0xF, 0xF, true); x += b.f; }
    QS_STEP(0x128)  // row_ror:8
    QS_STEP(0x124)  // row_ror:4
    QS_STEP(0x122)  // row_ror:2
    QS_STEP(0x121)  // row_ror:1
#undef QS_STEP
    return x;       // uniform within each 16-lane row
}

// ---------------------------------------------------------------------------
// Target-node features: xr = ((relu(LN(prev)) @ W + b) @ Wr + br) -> ws (fp32)
// block 0 = view branch, block 1 = scene branch. Also zeroes S/O accumulators.
// ---------------------------------------------------------------------------
__global__ __launch_bounds__(256)
void prep_k(const void* __restrict__ prev,
            const void* __restrict__ lns_v, const void* __restrict__ lnb_v,
            const void* __restrict__ W_v,   const void* __restrict__ b_v,
            const void* __restrict__ Wr_v,  const void* __restrict__ br_v,
            const void* __restrict__ lns_s, const void* __restrict__ lnb_s,
            const void* __restrict__ W_s,   const void* __restrict__ b_s,
            const void* __restrict__ Wr_s,  const void* __restrict__ br_s,
            float* __restrict__ xr, float* __restrict__ accSO)
{
    const bool f32 = !is_bf16(lns_v);
    const int br = blockIdx.x;
    const void* lns = br ? lns_s : lns_v;
    const void* lnb = br ? lnb_s : lnb_v;
    const void* W   = br ? W_s   : W_v;
    const void* bb  = br ? b_s   : b_v;
    const void* Wr  = br ? Wr_s  : Wr_v;
    const void* brr = br ? br_s  : br_v;
    const int t = threadIdx.x;
    for (int i = t; i < 264; i += 256) accSO[br*264 + i] = 0.f;

    __shared__ float g[512];
    __shared__ float xt[256];
    __shared__ float red[8];
    __shared__ float stats[2];
    float a0 = ldr(prev, t, f32), a1 = ldr(prev, t + 256, f32);
    float s1 = a0 + a1, s2 = a0*a0 + a1*a1;
#pragma unroll
    for (int s = 1; s < 64; s <<= 1) { s1 += __shfl_xor(s1, s); s2 += __shfl_xor(s2, s); }
    if ((t & 63) == 0) { red[t >> 6] = s1; red[4 + (t >> 6)] = s2; }
    __syncthreads();
    if (t == 0) {
        float a = 0.f, q = 0.f;
        for (int i = 0; i < 4; i++) { a += red[i]; q += red[4 + i]; }
        float mean = a / 512.f;
        stats[0] = mean;
        stats[1] = rsqrtf(q / 512.f - mean*mean + 1e-5f);
    }
    __syncthreads();
    float mean = stats[0], rstd = stats[1];
    g[t]       = fmaxf((a0 - mean)*rstd*ldr(lns, t, f32)       + ldr(lnb, t, f32), 0.f);
    g[t + 256] = fmaxf((a1 - mean)*rstd*ldr(lns, t + 256, f32) + ldr(lnb, t + 256, f32), 0.f);
    __syncthreads();
    float acc = 0.f;
#pragma unroll 16
    for (int i = 0; i < 512; i++) acc += g[i] * ldr(W, i*256 + t, f32);
    xt[t] = acc + ldr(bb, t, f32);
    __syncthreads();
    float acc2 = 0.f;
#pragma unroll 16
    for (int j = 0; j < 256; j++) acc2 += xt[j] * ldr(Wr, j*256 + t, f32);
    xr[br*256 + t] = acc2 + ldr(brr, t, f32);
}

// ---------------------------------------------------------------------------
// Main fused GAT, templated on input dtype; the mismatched instantiation exits
// immediately (both launched). xl = x@Wl + bl (bf16 MFMA), logits =
// leaky_relu(xl+xr)·att (DPP row reduction), UNNORMALIZED exp-sum per block
// merged via device-scope atomicAdd. One wave == one head. Double-buffered
// LDS, one barrier per K-tile, 2 blocks/CU.
// ---------------------------------------------------------------------------
template<bool F32>
__global__ __launch_bounds__(512, 4)
void gat_k(const void* __restrict__ view_x, const void* __restrict__ scene_x,
           const void* __restrict__ v_Wl, const void* __restrict__ s_Wl,
           const float* __restrict__ xr_all,
           const void* __restrict__ v_bl, const void* __restrict__ s_bl,
           const void* __restrict__ v_att, const void* __restrict__ s_att,
           const void* __restrict__ det,
           float* __restrict__ accSO)
{
    if (is_bf16(det) == F32) return;     // dtype mismatch -> dormant instantiation

    const int tid = threadIdx.x;
    const int wave = tid >> 6;          // == head (8 waves, H=8)
    const int lane = tid & 63;
    const int quad = lane >> 4;
    const int li   = lane & 15;

    const int bid = blockIdx.x;
    const bool scene = bid < NBS;
    const void* xsrc = scene ? scene_x : view_x;
    const void* Wl   = scene ? s_Wl : v_Wl;
    const float* xrp = xr_all + (scene ? 256 : 0);
    const void* blp  = scene ? s_bl  : v_bl;
    const void* attp = scene ? s_att : v_att;
    float* accR      = accSO + (scene ? 264 : 0);
    const int ntiles = scene ? 4096 : 64;
    const int nb     = scene ? NBS : NBV;
    const int slot   = scene ? bid : (bid - NBS);

    // B fragments: frag(nt,k)[j] = Wl[k*32 + quad*8 + j][wave*32 + nt*16 + li]
    bf16x8 Bf[2][8];
#pragma unroll
    for (int nt = 0; nt < 2; nt++)
#pragma unroll
        for (int k = 0; k < 8; k++) {
            union { ushort_t u[8]; bf16x8 v; } tmp;
#pragma unroll
            for (int j = 0; j < 8; j++) {
                int idx = (k*32 + quad*8 + j)*256 + (wave*32 + nt*16 + li);
                tmp.u[j] = F32 ? f2bf(((const float*)Wl)[idx]) : ((const ushort_t*)Wl)[idx];
            }
            Bf[nt][k] = tmp.v;
        }

    const int c0 = wave*32 + li;
    const float xr0 = xrp[c0],            xr1 = xrp[c0 + 16];
    const float at0 = ldr(attp, c0, F32), at1 = ldr(attp, c0 + 16, F32);
    const float bl0 = ldr(blp, c0, F32),  bl1 = ldr(blp, c0 + 16, F32);

    float Ssum = 0.f, oa0 = 0.f, oa1 = 0.f;

    __shared__ __align__(16) ushort_t alds[2][64 * SLDS];  // 66 KB double buffer

    // staging load of one (row, 8-col chunk) as 8 bf16 packed in int4
    auto stage = [&](int tile, int i) -> int4 {
        int f = tid + 512*i;
        int row = f >> 5, c8 = f & 31;
        size_t base = (size_t)(tile*64 + row)*256 + c8*8;
        if (F32) {
            const float* p = (const float*)xsrc + base;
            float4 a = *(const float4*)p, b = *(const float4*)(p + 4);
            union { ushort_t u[8]; int4 v; } t_;
            t_.u[0]=f2bf(a.x); t_.u[1]=f2bf(a.y); t_.u[2]=f2bf(a.z); t_.u[3]=f2bf(a.w);
            t_.u[4]=f2bf(b.x); t_.u[5]=f2bf(b.y); t_.u[6]=f2bf(b.z); t_.u[7]=f2bf(b.w);
            return t_.v;
        }
        return *(const int4*)((const ushort_t*)xsrc + base);
    };

    int4 pf[4];
    auto ldsw = [&](int b) {
#pragma unroll
        for (int i = 0; i < 4; i++) {
            int f = tid + 512*i;
            int row = f >> 5, c8 = f & 31;
            *(int4*)(&alds[b][row*SLDS + c8*8]) = pf[i];
        }
    };

    // preload tile 0 into buffer 0
#pragma unroll
    for (int i = 0; i < 4; i++) pf[i] = stage(slot, i);
    ldsw(0);
    __syncthreads();

    int buf = 0;
    for (int t = slot; t < ntiles; t += nb) {
        const int tn = t + nb;
        const bool more = tn < ntiles;
        if (more) {                      // issue next tile's global loads early
#pragma unroll
            for (int i = 0; i < 4; i++) pf[i] = stage(tn, i);
        }

        f32x4 acc[4][2] = {};            // 4 m-tiles x 2 n-tiles
#pragma unroll
        for (int k = 0; k < 8; k++) {
            bf16x8 a[4];
#pragma unroll
            for (int m = 0; m < 4; m++)
                a[m] = *(const bf16x8*)(&alds[buf][(m*16 + li)*SLDS + k*32 + quad*8]);
#pragma unroll
            for (int m = 0; m < 4; m++) {
                acc[m][0] = __builtin_amdgcn_mfma_f32_16x16x32_bf16(a[m], Bf[0][k], acc[m][0], 0, 0, 0);
                acc[m][1] = __builtin_amdgcn_mfma_f32_16x16x32_bf16(a[m], Bf[1][k], acc[m][1], 0, 0, 0);
            }
        }

        // epilogue: C/D layout col=lane&15, row=quad*4+reg (guide §3, m89-verified)
#pragma unroll
        for (int m = 0; m < 4; m++) {
#pragma unroll
            for (int r = 0; r < 4; r++) {
                float x0 = acc[m][0][r] + bl0;       // xl at (row, col li)
                float x1 = acc[m][1][r] + bl1;       // xl at (row, col li+16)
                float e0 = x0 + xr0; e0 = e0 > 0.f ? e0 : 0.2f*e0;
                float e1 = x1 + xr1; e1 = e1 > 0.f ? e1 : 0.2f*e1;
                float p = qsum16(at0*e0 + at1*e1);   // row logit, uniform in quad
                float w = __expf(fminf(p, 60.f));
                Ssum += w;
                oa0 += w * x0;
                oa1 += w * x1;
            }
        }

        if (more) ldsw(buf ^ 1);         // vmcnt wait lands here, after compute
        __syncthreads();                 // single barrier per iteration
        buf ^= 1;
    }

    // combine quads (each quad saw a disjoint set of rows; li is the column)
    Ssum += __shfl_xor(Ssum, 16); Ssum += __shfl_xor(Ssum, 32);
    oa0  += __shfl_xor(oa0, 16);  oa0  += __shfl_xor(oa0, 32);
    oa1  += __shfl_xor(oa1, 16);  oa1  += __shfl_xor(oa1, 32);

    if (lane == 0) atomicAdd(&accR[wave], Ssum);
    if (lane < 16) {
        atomicAdd(&accR[8 + wave*32 + lane],      oa0);
        atomicAdd(&accR[8 + wave*32 + 16 + lane], oa1);
    }
}

// ---------------------------------------------------------------------------
// out_gat[c] = O[c]/S[h] + bias; x = prev + out_gat; LN + relu -> xn; keep x_skip
// ---------------------------------------------------------------------------
__global__ __launch_bounds__(512)
void combine_k(const float* __restrict__ accSO,
               const void* __restrict__ prev,
               const void* __restrict__ v_bias, const void* __restrict__ s_bias,
               const void* __restrict__ pre_s, const void* __restrict__ pre_b,
               const void* __restrict__ det,
               float* __restrict__ x_skip, float* __restrict__ xn)
{
    const bool f32 = !is_bf16(det);
    const int t = threadIdx.x;
    const int branch = t >> 8, c = t & 255, h = c >> 5;
    float S = accSO[branch*264 + h];
    float o = accSO[branch*264 + 8 + c];
    const void* bias = branch ? s_bias : v_bias;
    float xv = ldr(prev, t, f32) + o / S + ldr(bias, c, f32);
    x_skip[t] = xv;
    __shared__ float red[16];
    __shared__ float stats[2];
    float s1 = xv, s2 = xv*xv;
#pragma unroll
    for (int s = 1; s < 64; s <<= 1) { s1 += __shfl_xor(s1, s); s2 += __shfl_xor(s2, s); }
    if ((t & 63) == 0) { red[t >> 6] = s1; red[8 + (t >> 6)] = s2; }
    __syncthreads();
    if (t == 0) {
        float a = 0.f, q = 0.f;
        for (int i = 0; i < 8; i++) { a += red[i]; q += red[8 + i]; }
        float mean = a / 512.f;
        stats[0] = mean;
        stats[1] = rsqrtf(q / 512.f - mean*mean + 1e-5f);
    }
    __syncthreads();
    float xnv = (xv - stats[0]) * stats[1] * ldr(pre_s, t, f32) + ldr(pre_b, t, f32);
    xn[t] = fmaxf(xnv, 0.f);
}

// ---------------------------------------------------------------------------
// out = x_skip + xn @ mlp_W + mlp_b   (2 blocks x 256 cols)
// ---------------------------------------------------------------------------
__global__ __launch_bounds__(256)
void mlp_k(const float* __restrict__ x_skip, const float* __restrict__ xn,
           const void* __restrict__ W, const void* __restrict__ mb,
           const void* __restrict__ det,
           void* __restrict__ out)
{
    const bool f32 = !is_bf16(det);
    __shared__ float xs[512];
    const int t = threadIdx.x;
    const int col = blockIdx.x*256 + t;
    for (int i = t; i < 512; i += 256) xs[i] = xn[i];
    __syncthreads();
    float acc = 0.f;
#pragma unroll 16
    for (int i = 0; i < 512; i++) acc += xs[i] * ldr(W, i*512 + col, f32);
    float r = x_skip[col] + acc + ldr(mb, col, f32);
    if (f32) ((float*)out)[col] = r;
    else     ((ushort_t*)out)[col] = f2bf(r);
}

extern "C" void kernel_launch(void* const* d_in, const int* in_sizes, int n_in,
                              void* d_out, int out_size, void* d_ws, size_t ws_size,
                              hipStream_t stream)
{
    const void* view_x  = d_in[0];
    const void* scene_x = d_in[1];
    const void* prev    = d_in[2];
    const void* g2v_lns = d_in[3];   // ones(512) -> dtype detector
    const void* g2v_lnb = d_in[4];
    const void* g2v_W   = d_in[5];
    const void* g2v_b   = d_in[6];
    const void* g2s_lns = d_in[7];
    const void* g2s_lnb = d_in[8];
    const void* g2s_W   = d_in[9];
    const void* g2s_b   = d_in[10];
    const void* v_Wl    = d_in[11];
    const void* v_bl    = d_in[12];
    const void* v_Wr    = d_in[13];
    const void* v_br    = d_in[14];
    const void* v_att   = d_in[15];
    const void* v_bias  = d_in[16];
    const void* s_Wl    = d_in[17];
    const void* s_bl    = d_in[18];
    const void* s_Wr    = d_in[19];
    const void* s_br    = d_in[20];
    const void* s_att   = d_in[21];
    const void* s_bias  = d_in[22];
    const void* pre_s   = d_in[23];
    const void* pre_b   = d_in[24];
    const void* mlp_W   = d_in[25];
    const void* mlp_b   = d_in[26];

    float* wsf    = (float*)d_ws;
    float* xr     = wsf + WS_XR;
    float* accSO  = wsf + WS_ACC;
    float* x_skip = wsf + WS_SKIP;
    float* xn     = wsf + WS_XN;

    prep_k<<<dim3(2), dim3(256), 0, stream>>>(prev,
                                              g2v_lns, g2v_lnb, g2v_W, g2v_b, v_Wr, v_br,
                                              g2s_lns, g2s_lnb, g2s_W, g2s_b, s_Wr, s_br,
                                              xr, accSO);
    gat_k<false><<<dim3(NBS + NBV), dim3(512), 0, stream>>>(view_x, scene_x, v_Wl, s_Wl, xr,
                                                            v_bl, s_bl, v_att, s_att,
                                                            g2v_lns, accSO);
    gat_k<true><<<dim3(NBS + NBV), dim3(512), 0, stream>>>(view_x, scene_x, v_Wl, s_Wl, xr,
                                                           v_bl, s_bl, v_att, s_att,
                                                           g2v_lns, accSO);
    combine_k<<<dim3(1), dim3(512), 0, stream>>>(accSO, prev, v_bias, s_bias,
                                                 pre_s, pre_b, g2v_lns, x_skip, xn);
    mlp_k<<<dim3(2), dim3(256), 0, stream>>>(x_skip, xn, mlp_W, mlp_b, g2v_lns, d_out);
}

// Round 5
// 562.473 us; speedup vs baseline: 1.1781x; 1.0756x over previous
//
#include <hip/hip_runtime.h>
#include <hip/hip_bf16.h>

typedef unsigned short ushort_t;
typedef __attribute__((ext_vector_type(8))) short bf16x8;   // 8 bf16 = 4 VGPRs (guide §3)
typedef __attribute__((ext_vector_type(4))) float f32x4;

#define NBS 480   // scene blocks (4096 tiles, strided)
#define NBV 32    // view blocks  (64 tiles, 2 each)
#define SLDS 264  // LDS row stride in bf16 (256 + 8 pad)

// ws layout (floats): [0,512) xr | [512,1040) S/O accum | [1040,1552) x_skip | [1552,2064) xn
#define WS_XR    0
#define WS_ACC   512
#define WS_SKIP  1040
#define WS_XN    1552

__device__ __forceinline__ float bf2f(ushort_t u) {
    union { unsigned int i; float f; } v; v.i = ((unsigned int)u) << 16; return v.f;
}
__device__ __forceinline__ ushort_t f2bf(float f) {
    union { float f; unsigned int i; } v; v.f = f;
    unsigned int x = v.i;
    return (ushort_t)((x + 0x7fffu + ((x >> 16) & 1u)) >> 16);   // RNE
}
// compile-time-typed load: straight-line, batchable (no runtime branch!)
template<bool F32>
__device__ __forceinline__ float ldT(const void* p, int i) {
    if (F32) return ((const float*)p)[i];
    return bf2f(((const ushort_t*)p)[i]);
}
// detection: g2v_ln_s == ones. bf16 ones -> ushort[0]=0x3F80; fp32 ones -> 0x0000.
__device__ __forceinline__ bool is_bf16(const void* det) {
    return ((const ushort_t*)det)[0] == 0x3F80u;
}

// Sum x across each 16-lane DPP row (== quad group; li = lane&15). 4 VALU adds, no LDS.
__device__ __forceinline__ float qsum16(float x) {
    union { float f; int i; } a, b;
#define QS_STEP(CTRL) { a.f = x; b.i = __builtin_amdgcn_update_dpp(0, a.i, CTRL, 0xF, 0xF, true); x += b.f; }
    QS_STEP(0x128)  // row_ror:8
    QS_STEP(0x124)  // row_ror:4
    QS_STEP(0x122)  // row_ror:2
    QS_STEP(0x121)  // row_ror:1
#undef QS_STEP
    return x;       // uniform within each 16-lane row
}

// ---------------------------------------------------------------------------
// Target-node features: xr = ((relu(LN(prev)) @ W + b) @ Wr + br) -> ws (fp32)
// 512 threads: GEMVs split K across 2 thread-halves, LDS-combined.
// block 0 = view branch, block 1 = scene branch. Also zeroes S/O accumulators.
// ---------------------------------------------------------------------------
template<bool F32>
__global__ __launch_bounds__(512)
void prep_k(const void* __restrict__ prev,
            const void* __restrict__ lns_v, const void* __restrict__ lnb_v,
            const void* __restrict__ W_v,   const void* __restrict__ b_v,
            const void* __restrict__ Wr_v,  const void* __restrict__ br_v,
            const void* __restrict__ lns_s, const void* __restrict__ lnb_s,
            const void* __restrict__ W_s,   const void* __restrict__ b_s,
            const void* __restrict__ Wr_s,  const void* __restrict__ br_s,
            float* __restrict__ xr, float* __restrict__ accSO)
{
    if (is_bf16(lns_v) == F32) return;   // dormant flavor
    const int br = blockIdx.x;
    const void* lns = br ? lns_s : lns_v;
    const void* lnb = br ? lnb_s : lnb_v;
    const void* W   = br ? W_s   : W_v;
    const void* bb  = br ? b_s   : b_v;
    const void* Wr  = br ? Wr_s  : Wr_v;
    const void* brr = br ? br_s  : br_v;
    const int t = threadIdx.x;
    for (int i = t; i < 264; i += 512) accSO[br*264 + i] = 0.f;

    __shared__ float g[512];
    __shared__ float xt[256];
    __shared__ float red[16];
    __shared__ float stats[2];
    __shared__ float part[512];

    float a0 = ldT<F32>(prev, t);
    float s1 = a0, s2 = a0*a0;
#pragma unroll
    for (int s = 1; s < 64; s <<= 1) { s1 += __shfl_xor(s1, s); s2 += __shfl_xor(s2, s); }
    if ((t & 63) == 0) { red[t >> 6] = s1; red[8 + (t >> 6)] = s2; }
    __syncthreads();
    if (t == 0) {
        float a = 0.f, q = 0.f;
        for (int i = 0; i < 8; i++) { a += red[i]; q += red[8 + i]; }
        float mean = a / 512.f;
        stats[0] = mean;
        stats[1] = rsqrtf(q / 512.f - mean*mean + 1e-5f);
    }
    __syncthreads();
    g[t] = fmaxf((a0 - stats[0])*stats[1]*ldT<F32>(lns, t) + ldT<F32>(lnb, t), 0.f);
    __syncthreads();

    // GEMV1: [512]x[512,256] -> xt[256]; thread (kh = t>>8, c = t&255) sums 256 K
    const int c = t & 255, kh = t >> 8;
    {
        const int base = kh * 256;
        float acc = 0.f;
#pragma unroll 8
        for (int i = 0; i < 256; i++) acc += g[base + i] * ldT<F32>(W, (base + i)*256 + c);
        part[t] = acc;
    }
    __syncthreads();
    if (t < 256) xt[t] = part[t] + part[t + 256] + ldT<F32>(bb, t);
    __syncthreads();

    // GEMV2: [256]x[256,256] -> xr[256]; thread (kh, c) sums 128 K
    {
        const int b2 = kh * 128;
        float acc2 = 0.f;
#pragma unroll 8
        for (int j = 0; j < 128; j++) acc2 += xt[b2 + j] * ldT<F32>(Wr, (b2 + j)*256 + c);
        part[t] = acc2;
    }
    __syncthreads();
    if (t < 256) xr[br*256 + t] = part[t] + part[t + 256] + ldT<F32>(brr, t);
}

// ---------------------------------------------------------------------------
// Main fused GAT. xl = x@Wl + bl (bf16 MFMA), logits = leaky_relu(xl+xr)·att
// (DPP row reduction), UNNORMALIZED exp-sum per block merged via device-scope
// atomicAdd. One wave == one head. Double-buffered LDS + 2-deep global
// prefetch (pf[2][4]; FIFO vmcnt keeps the younger 4 loads in flight).
// launch_bounds(512,2): 256-reg cap -> NO spills (round-3-proven).
// ---------------------------------------------------------------------------
template<bool F32>
__global__ __launch_bounds__(512, 2)
void gat_k(const void* __restrict__ view_x, const void* __restrict__ scene_x,
           const void* __restrict__ v_Wl, const void* __restrict__ s_Wl,
           const float* __restrict__ xr_all,
           const void* __restrict__ v_bl, const void* __restrict__ s_bl,
           const void* __restrict__ v_att, const void* __restrict__ s_att,
           const void* __restrict__ det,
           float* __restrict__ accSO)
{
    if (is_bf16(det) == F32) return;     // dormant flavor

    const int tid = threadIdx.x;
    const int wave = tid >> 6;          // == head (8 waves, H=8)
    const int lane = tid & 63;
    const int quad = lane >> 4;
    const int li   = lane & 15;

    const int bid = blockIdx.x;
    const bool scene = bid < NBS;
    const void* xsrc = scene ? scene_x : view_x;
    const void* Wl   = scene ? s_Wl : v_Wl;
    const float* xrp = xr_all + (scene ? 256 : 0);
    const void* blp  = scene ? s_bl  : v_bl;
    const void* attp = scene ? s_att : v_att;
    float* accR      = accSO + (scene ? 264 : 0);
    const int ntiles = scene ? 4096 : 64;
    const int nb     = scene ? NBS : NBV;
    const int slot   = scene ? bid : (bid - NBS);

    // B fragments: frag(nt,k)[j] = Wl[k*32 + quad*8 + j][wave*32 + nt*16 + li]
    bf16x8 Bf[2][8];
#pragma unroll
    for (int nt = 0; nt < 2; nt++)
#pragma unroll
        for (int k = 0; k < 8; k++) {
            union { ushort_t u[8]; bf16x8 v; } tmp;
#pragma unroll
            for (int j = 0; j < 8; j++) {
                int idx = (k*32 + quad*8 + j)*256 + (wave*32 + nt*16 + li);
                tmp.u[j] = F32 ? f2bf(((const float*)Wl)[idx]) : ((const ushort_t*)Wl)[idx];
            }
            Bf[nt][k] = tmp.v;
        }

    const int c0 = wave*32 + li;
    const float xr0 = xrp[c0],             xr1 = xrp[c0 + 16];
    const float at0 = ldT<F32>(attp, c0),  at1 = ldT<F32>(attp, c0 + 16);
    const float bl0 = ldT<F32>(blp, c0),   bl1 = ldT<F32>(blp, c0 + 16);

    float Ssum = 0.f, oa0 = 0.f, oa1 = 0.f;

    __shared__ __align__(16) ushort_t alds[2][64 * SLDS];  // 66 KB double buffer

    auto stage = [&](int tile, int i) -> int4 {
        int f = tid + 512*i;
        int row = f >> 5, c8 = f & 31;
        size_t base = (size_t)(tile*64 + row)*256 + c8*8;
        if (F32) {
            const float* p = (const float*)xsrc + base;
            float4 a = *(const float4*)p, b = *(const float4*)(p + 4);
            union { ushort_t u[8]; int4 v; } t_;
            t_.u[0]=f2bf(a.x); t_.u[1]=f2bf(a.y); t_.u[2]=f2bf(a.z); t_.u[3]=f2bf(a.w);
            t_.u[4]=f2bf(b.x); t_.u[5]=f2bf(b.y); t_.u[6]=f2bf(b.z); t_.u[7]=f2bf(b.w);
            return t_.v;
        }
        return *(const int4*)((const ushort_t*)xsrc + base);
    };
    auto ldsw = [&](int b, int4* src) {
#pragma unroll
        for (int i = 0; i < 4; i++) {
            int f = tid + 512*i;
            int row = f >> 5, c8 = f & 31;
            *(int4*)(&alds[b][row*SLDS + c8*8]) = src[i];
        }
    };

    int4 pf[2][4];
    {   // prologue: tile0 -> LDS; issue tiles t+1 (pf[0]) and t+2 (pf[1])
        int4 t0[4];
#pragma unroll
        for (int i = 0; i < 4; i++) t0[i] = stage(slot, i);
        ldsw(0, t0);
        if (slot + nb < ntiles) {
#pragma unroll
            for (int i = 0; i < 4; i++) pf[0][i] = stage(slot + nb, i);
        }
        if (slot + 2*nb < ntiles) {
#pragma unroll
            for (int i = 0; i < 4; i++) pf[1][i] = stage(slot + 2*nb, i);
        }
        __syncthreads();
    }

    int buf = 0, par = 0;
    for (int t = slot; t < ntiles; t += nb) {
        f32x4 acc[4][2] = {};            // 4 m-tiles x 2 n-tiles
#pragma unroll
        for (int k = 0; k < 8; k++) {
            bf16x8 a[4];
#pragma unroll
            for (int m = 0; m < 4; m++)
                a[m] = *(const bf16x8*)(&alds[buf][(m*16 + li)*SLDS + k*32 + quad*8]);
#pragma unroll
            for (int m = 0; m < 4; m++) {
                acc[m][0] = __builtin_amdgcn_mfma_f32_16x16x32_bf16(a[m], Bf[0][k], acc[m][0], 0, 0, 0);
                acc[m][1] = __builtin_amdgcn_mfma_f32_16x16x32_bf16(a[m], Bf[1][k], acc[m][1], 0, 0, 0);
            }
        }

        // epilogue: C/D layout col=lane&15, row=quad*4+reg (guide §3, m89-verified)
#pragma unroll
        for (int m = 0; m < 4; m++) {
#pragma unroll
            for (int r = 0; r < 4; r++) {
                float x0 = acc[m][0][r] + bl0;       // xl at (row, col li)
                float x1 = acc[m][1][r] + bl1;       // xl at (row, col li+16)
                float e0 = x0 + xr0; e0 = e0 > 0.f ? e0 : 0.2f*e0;
                float e1 = x1 + xr1; e1 = e1 > 0.f ? e1 : 0.2f*e1;
                float p = qsum16(at0*e0 + at1*e1);   // row logit, uniform in quad
                float w = __expf(fminf(p, 60.f));
                Ssum += w;
                oa0 += w * x0;
                oa1 += w * x1;
            }
        }

        if (t + nb < ntiles) {
            ldsw(buf ^ 1, pf[par]);      // waits only the OLDER 4 loads (vmcnt(4))
            int tf = t + 3*nb;
            if (tf < ntiles) {
#pragma unroll
                for (int i = 0; i < 4; i++) pf[par][i] = stage(tf, i);
            }
        }
        __syncthreads();
        buf ^= 1; par ^= 1;
    }

    // combine quads (each quad saw a disjoint set of rows; li is the column)
    Ssum += __shfl_xor(Ssum, 16); Ssum += __shfl_xor(Ssum, 32);
    oa0  += __shfl_xor(oa0, 16);  oa0  += __shfl_xor(oa0, 32);
    oa1  += __shfl_xor(oa1, 16);  oa1  += __shfl_xor(oa1, 32);

    if (lane == 0) atomicAdd(&accR[wave], Ssum);
    if (lane < 16) {
        atomicAdd(&accR[8 + wave*32 + lane],      oa0);
        atomicAdd(&accR[8 + wave*32 + 16 + lane], oa1);
    }
}

// ---------------------------------------------------------------------------
// out_gat[c] = O[c]/S[h] + bias; x = prev + out_gat; LN + relu -> xn; keep x_skip
// ---------------------------------------------------------------------------
template<bool F32>
__global__ __launch_bounds__(512)
void combine_k(const float* __restrict__ accSO,
               const void* __restrict__ prev,
               const void* __restrict__ v_bias, const void* __restrict__ s_bias,
               const void* __restrict__ pre_s, const void* __restrict__ pre_b,
               const void* __restrict__ det,
               float* __restrict__ x_skip, float* __restrict__ xn)
{
    if (is_bf16(det) == F32) return;
    const int t = threadIdx.x;
    const int branch = t >> 8, c = t & 255, h = c >> 5;
    float S = accSO[branch*264 + h];
    float o = accSO[branch*264 + 8 + c];
    const void* bias = branch ? s_bias : v_bias;
    float xv = ldT<F32>(prev, t) + o / S + ldT<F32>(bias, c);
    x_skip[t] = xv;
    __shared__ float red[16];
    __shared__ float stats[2];
    float s1 = xv, s2 = xv*xv;
#pragma unroll
    for (int s = 1; s < 64; s <<= 1) { s1 += __shfl_xor(s1, s); s2 += __shfl_xor(s2, s); }
    if ((t & 63) == 0) { red[t >> 6] = s1; red[8 + (t >> 6)] = s2; }
    __syncthreads();
    if (t == 0) {
        float a = 0.f, q = 0.f;
        for (int i = 0; i < 8; i++) { a += red[i]; q += red[8 + i]; }
        float mean = a / 512.f;
        stats[0] = mean;
        stats[1] = rsqrtf(q / 512.f - mean*mean + 1e-5f);
    }
    __syncthreads();
    float xnv = (xv - stats[0]) * stats[1] * ldT<F32>(pre_s, t) + ldT<F32>(pre_b, t);
    xn[t] = fmaxf(xnv, 0.f);
}

// ---------------------------------------------------------------------------
// out = x_skip + xn @ mlp_W + mlp_b   (4 blocks x 128 cols, K split 2x256)
// ---------------------------------------------------------------------------
template<bool F32>
__global__ __launch_bounds__(256)
void mlp_k(const float* __restrict__ x_skip, const float* __restrict__ xn,
           const void* __restrict__ W, const void* __restrict__ mb,
           const void* __restrict__ det,
           void* __restrict__ out)
{
    if (is_bf16(det) == F32) return;
    __shared__ float xs[512];
    __shared__ float part[256];
    const int t = threadIdx.x;
    for (int i = t; i < 512; i += 256) xs[i] = xn[i];
    __syncthreads();
    const int c = blockIdx.x*128 + (t & 127);
    const int kh = t >> 7;
    const int b = kh * 256;
    float acc = 0.f;
#pragma unroll 8
    for (int i = 0; i < 256; i++) acc += xs[b + i] * ldT<F32>(W, (b + i)*512 + c);
    part[t] = acc;
    __syncthreads();
    if (t < 128) {
        float r = x_skip[c] + part[t] + part[t + 128] + ldT<F32>(mb, c);
        if (F32) ((float*)out)[c] = r;
        else     ((ushort_t*)out)[c] = f2bf(r);
    }
}

extern "C" void kernel_launch(void* const* d_in, const int* in_sizes, int n_in,
                              void* d_out, int out_size, void* d_ws, size_t ws_size,
                              hipStream_t stream)
{
    const void* view_x  = d_in[0];
    const void* scene_x = d_in[1];
    const void* prev    = d_in[2];
    const void* g2v_lns = d_in[3];   // ones(512) -> dtype detector
    const void* g2v_lnb = d_in[4];
    const void* g2v_W   = d_in[5];
    const void* g2v_b   = d_in[6];
    const void* g2s_lns = d_in[7];
    const void* g2s_lnb = d_in[8];
    const void* g2s_W   = d_in[9];
    const void* g2s_b   = d_in[10];
    const void* v_Wl    = d_in[11];
    const void* v_bl    = d_in[12];
    const void* v_Wr    = d_in[13];
    const void* v_br    = d_in[14];
    const void* v_att   = d_in[15];
    const void* v_bias  = d_in[16];
    const void* s_Wl    = d_in[17];
    const void* s_bl    = d_in[18];
    const void* s_Wr    = d_in[19];
    const void* s_br    = d_in[20];
    const void* s_att   = d_in[21];
    const void* s_bias  = d_in[22];
    const void* pre_s   = d_in[23];
    const void* pre_b   = d_in[24];
    const void* mlp_W   = d_in[25];
    const void* mlp_b   = d_in[26];

    float* wsf    = (float*)d_ws;
    float* xr     = wsf + WS_XR;
    float* accSO  = wsf + WS_ACC;
    float* x_skip = wsf + WS_SKIP;
    float* xn     = wsf + WS_XN;

    prep_k<false><<<dim3(2), dim3(512), 0, stream>>>(prev,
                                              g2v_lns, g2v_lnb, g2v_W, g2v_b, v_Wr, v_br,
                                              g2s_lns, g2s_lnb, g2s_W, g2s_b, s_Wr, s_br,
                                              xr, accSO);
    prep_k<true><<<dim3(2), dim3(512), 0, stream>>>(prev,
                                              g2v_lns, g2v_lnb, g2v_W, g2v_b, v_Wr, v_br,
                                              g2s_lns, g2s_lnb, g2s_W, g2s_b, s_Wr, s_br,
                                              xr, accSO);
    gat_k<false><<<dim3(NBS + NBV), dim3(512), 0, stream>>>(view_x, scene_x, v_Wl, s_Wl, xr,
                                                            v_bl, s_bl, v_att, s_att,
                                                            g2v_lns, accSO);
    gat_k<true><<<dim3(NBS + NBV), dim3(512), 0, stream>>>(view_x, scene_x, v_Wl, s_Wl, xr,
                                                           v_bl, s_bl, v_att, s_att,
                                                           g2v_lns, accSO);
    combine_k<false><<<dim3(1), dim3(512), 0, stream>>>(accSO, prev, v_bias, s_bias,
                                                        pre_s, pre_b, g2v_lns, x_skip, xn);
    combine_k<true><<<dim3(1), dim3(512), 0, stream>>>(accSO, prev, v_bias, s_bias,
                                                       pre_s, pre_b, g2v_lns, x_skip, xn);
    mlp_k<false><<<dim3(4), dim3(256), 0, stream>>>(x_skip, xn, mlp_W, mlp_b, g2v_lns, d_out);
    mlp_k<true><<<dim3(4), dim3(256), 0, stream>>>(x_skip, xn, mlp_W, mlp_b, g2v_lns, d_out);
}

// Round 6
// 505.385 us; speedup vs baseline: 1.3112x; 1.1130x over previous
//
#include <hip/hip_runtime.h>
#include <hip/hip_bf16.h>

typedef unsigned short ushort_t;
typedef __attribute__((ext_vector_type(8))) short bf16x8;   // 8 bf16 = 4 VGPRs
typedef __attribute__((ext_vector_type(4))) float f32x4;

#define NSCENE 4096   // scene tiles of 64 rows (262144/64)
#define NVIEW  64     // view  tiles of 64 rows (4096/64)
#define NBUCK  16     // atomic accumulator buckets (bid & 15)

// ws layout (floats): [0,512) xr | [512, 512+NBUCK*528) buckets | then x_skip, xn
#define WS_XR    0
#define WS_ACC   512
#define WS_SKIP  (512 + NBUCK*528)          // 8960
#define WS_XN    (WS_SKIP + 512)            // 9472  -> total 9984 floats = 40 KB

__device__ __forceinline__ float bf2f(ushort_t u) {
    union { unsigned int i; float f; } v; v.i = ((unsigned int)u) << 16; return v.f;
}
__device__ __forceinline__ ushort_t f2bf(float f) {
    union { float f; unsigned int i; } v; v.f = f;
    unsigned int x = v.i;
    return (ushort_t)((x + 0x7fffu + ((x >> 16) & 1u)) >> 16);   // RNE
}
template<bool F32>
__device__ __forceinline__ float ldT(const void* p, int i) {
    if (F32) return ((const float*)p)[i];
    return bf2f(((const ushort_t*)p)[i]);
}
// detection: g2v_ln_s == ones. bf16 ones -> ushort[0]=0x3F80; fp32 ones -> 0x0000.
__device__ __forceinline__ bool is_bf16(const void* det) {
    return ((const ushort_t*)det)[0] == 0x3F80u;
}
// async global->LDS DMA, 16 B per lane; lds base must be wave-uniform,
// HW scatters lane l at base + l*16 (guide §5, m97). Counts in vmcnt.
__device__ __forceinline__ void async16(const void* g, void* lds) {
    __builtin_amdgcn_global_load_lds(
        (const __attribute__((address_space(1))) unsigned int*)g,
        (__attribute__((address_space(3))) unsigned int*)lds, 16, 0, 0);
}
// Sum across each 16-lane DPP row (quad group; li = lane&15). Pure VALU.
__device__ __forceinline__ float qsum16(float x) {
    union { float f; int i; } a, b;
#define QS_STEP(CTRL) { a.f = x; b.i = __builtin_amdgcn_update_dpp(0, a.i, CTRL, 0xF, 0xF, true); x += b.f; }
    QS_STEP(0x128)  // row_ror:8
    QS_STEP(0x124)  // row_ror:4
    QS_STEP(0x122)  // row_ror:2
    QS_STEP(0x121)  // row_ror:1
#undef QS_STEP
    return x;
}

// ---------------------------------------------------------------------------
// Target-node features: xr = ((relu(LN(prev)) @ W + b) @ Wr + br) -> ws (fp32)
// block 0 = view, block 1 = scene. Also zeroes this branch's bucket accums.
// GEMVs: K-split x2 across thread halves, 32-deep explicit load batches.
// ---------------------------------------------------------------------------
template<bool F32>
__global__ __launch_bounds__(512)
void prep_k(const void* __restrict__ prev,
            const void* __restrict__ lns_v, const void* __restrict__ lnb_v,
            const void* __restrict__ W_v,   const void* __restrict__ b_v,
            const void* __restrict__ Wr_v,  const void* __restrict__ br_v,
            const void* __restrict__ lns_s, const void* __restrict__ lnb_s,
            const void* __restrict__ W_s,   const void* __restrict__ b_s,
            const void* __restrict__ Wr_s,  const void* __restrict__ br_s,
            float* __restrict__ xr, float* __restrict__ accSO)
{
    if (is_bf16(lns_v) == F32) return;   // dormant flavor
    const int br = blockIdx.x;
    const void* lns = br ? lns_s : lns_v;
    const void* lnb = br ? lnb_s : lnb_v;
    const void* W   = br ? W_s   : W_v;
    const void* bb  = br ? b_s   : b_v;
    const void* Wr  = br ? Wr_s  : Wr_v;
    const void* brr = br ? br_s  : br_v;
    const int t = threadIdx.x;
    // zero this branch's half of every bucket
#pragma unroll
    for (int b = 0; b < NBUCK; b++)
        for (int i = t; i < 264; i += 512) accSO[b*528 + br*264 + i] = 0.f;

    __shared__ float g[512];
    __shared__ float xt[256];
    __shared__ float red[16];
    __shared__ float stats[2];
    __shared__ float part[512];

    float a0 = ldT<F32>(prev, t);
    float s1 = a0, s2 = a0*a0;
#pragma unroll
    for (int s = 1; s < 64; s <<= 1) { s1 += __shfl_xor(s1, s); s2 += __shfl_xor(s2, s); }
    if ((t & 63) == 0) { red[t >> 6] = s1; red[8 + (t >> 6)] = s2; }
    __syncthreads();
    if (t == 0) {
        float a = 0.f, q = 0.f;
        for (int i = 0; i < 8; i++) { a += red[i]; q += red[8 + i]; }
        float mean = a / 512.f;
        stats[0] = mean;
        stats[1] = rsqrtf(q / 512.f - mean*mean + 1e-5f);
    }
    __syncthreads();
    g[t] = fmaxf((a0 - stats[0])*stats[1]*ldT<F32>(lns, t) + ldT<F32>(lnb, t), 0.f);
    __syncthreads();

    const int c = t & 255, kh = t >> 8;
    {   // GEMV1: [512]x[512,256] -> xt; thread sums 256 K, batched 32
        const int base = kh * 256;
        float acc = 0.f;
        for (int ii = 0; ii < 256; ii += 32) {
            float wv[32];
#pragma unroll
            for (int u = 0; u < 32; u++) wv[u] = ldT<F32>(W, (base + ii + u)*256 + c);
#pragma unroll
            for (int u = 0; u < 32; u++) acc += g[base + ii + u] * wv[u];
        }
        part[t] = acc;
    }
    __syncthreads();
    if (t < 256) xt[t] = part[t] + part[t + 256] + ldT<F32>(bb, t);
    __syncthreads();
    {   // GEMV2: [256]x[256,256] -> xr; thread sums 128 K, batched 32
        const int b2 = kh * 128;
        float acc2 = 0.f;
        for (int ii = 0; ii < 128; ii += 32) {
            float wv[32];
#pragma unroll
            for (int u = 0; u < 32; u++) wv[u] = ldT<F32>(Wr, (b2 + ii + u)*256 + c);
#pragma unroll
            for (int u = 0; u < 32; u++) acc2 += xt[b2 + ii + u] * wv[u];
        }
        part[t] = acc2;
    }
    __syncthreads();
    if (t < 256) xr[br*256 + t] = part[t] + part[t + 256] + ldT<F32>(brr, t);
}

// ---------------------------------------------------------------------------
// Main fused GAT, one-shot tile blocks. Block = one 64-row tile: async-DMA the
// tile into XOR-swizzled LDS, one barrier, 64 MFMAs/wave, epilogue, bucketed
// atomic merge. Wave == head. No K-loop, no double-buffer, no VGPR staging.
// LDS image: row-major 64x256 bf16, group-of-8 index swizzled g' = g ^ (row&7)
//   -> ds_read_b128 A-frags hit 8 banks x 2-way (free, m136).
// ---------------------------------------------------------------------------
template<bool F32>
__global__ __launch_bounds__(512, 2)
void gat_k(const void* __restrict__ view_x, const void* __restrict__ scene_x,
           const void* __restrict__ v_Wl, const void* __restrict__ s_Wl,
           const float* __restrict__ xr_all,
           const void* __restrict__ v_bl, const void* __restrict__ s_bl,
           const void* __restrict__ v_att, const void* __restrict__ s_att,
           const void* __restrict__ det,
           float* __restrict__ accSO)
{
    if (is_bf16(det) == F32) return;     // dormant flavor

    const int tid  = threadIdx.x;
    const int wave = tid >> 6;          // == head
    const int lane = tid & 63;
    const int quad = lane >> 4;
    const int li   = lane & 15;

    const int bid   = blockIdx.x;
    const bool scene = bid < NSCENE;
    const void* xsrc = scene ? scene_x : view_x;
    const void* Wl   = scene ? s_Wl : v_Wl;
    const float* xrp = xr_all + (scene ? 256 : 0);
    const void* blp  = scene ? s_bl  : v_bl;
    const void* attp = scene ? s_att : v_att;
    float* accR      = accSO + (bid & (NBUCK - 1))*528 + (scene ? 264 : 0);
    const int tile   = scene ? bid : (bid - NSCENE);

    __shared__ __align__(16) ushort_t alds[64 * 256];   // 32 KB, swizzled

    // ---- stage tile: 32 chunks of 1 KB (2 rows each); wave w -> chunks w*4..w*4+3
    // lane l: row = 2*ci + (l>>5); LDS group g' = l&31; global group g = g' ^ (row&7)
    {
        const int l5 = lane >> 5, g2 = lane & 31;
#pragma unroll
        for (int j = 0; j < 4; j++) {
            const int ci  = wave*4 + j;
            const int row = 2*ci + l5;
            const int g   = (g2 & 24) | ((g2 & 7) ^ (row & 7));
            const size_t gelem = (size_t)(tile*64 + row)*256 + g*8;
            if (F32) {
                const float* p = (const float*)xsrc + gelem;
                float4 a = *(const float4*)p, b = *(const float4*)(p + 4);
                union { ushort_t u[8]; int4 v; } t_;
                t_.u[0]=f2bf(a.x); t_.u[1]=f2bf(a.y); t_.u[2]=f2bf(a.z); t_.u[3]=f2bf(a.w);
                t_.u[4]=f2bf(b.x); t_.u[5]=f2bf(b.y); t_.u[6]=f2bf(b.z); t_.u[7]=f2bf(b.w);
                *(int4*)(&alds[ci*512 + lane*8]) = t_.v;
            } else {
                async16((const ushort_t*)xsrc + gelem, &alds[ci*512]);  // base wave-uniform
            }
        }
    }

    // ---- B fragments (overlap DMA): frag(nt,k)[j] = Wl[k*32+quad*8+j][wave*32+nt*16+li]
    bf16x8 Bf[2][8];
#pragma unroll
    for (int nt = 0; nt < 2; nt++)
#pragma unroll
        for (int k = 0; k < 8; k++) {
            union { ushort_t u[8]; bf16x8 v; } tmp;
#pragma unroll
            for (int j = 0; j < 8; j++) {
                int idx = (k*32 + quad*8 + j)*256 + (wave*32 + nt*16 + li);
                tmp.u[j] = F32 ? f2bf(((const float*)Wl)[idx]) : ((const ushort_t*)Wl)[idx];
            }
            Bf[nt][k] = tmp.v;
        }

    const int c0 = wave*32 + li;
    const float xr0 = xrp[c0],            xr1 = xrp[c0 + 16];
    const float at0 = ldT<F32>(attp, c0), at1 = ldT<F32>(attp, c0 + 16);
    const float bl0 = ldT<F32>(blp, c0),  bl1 = ldT<F32>(blp, c0 + 16);

    __syncthreads();   // drains vmcnt (DMA + gathers) then barrier

    // ---- compute: 4 m-tiles x 2 n-tiles x 8 k-steps
    f32x4 acc[4][2] = {};
#pragma unroll
    for (int k = 0; k < 8; k++) {
        bf16x8 a[4];
#pragma unroll
        for (int m = 0; m < 4; m++) {
            const int r  = m*16 + li;
            const int gq = k*4 + quad;
            const int gp = (gq & 24) | ((gq & 7) ^ (li & 7));   // un-swizzle (row&7 == li&7)
            a[m] = *(const bf16x8*)(&alds[r*256 + gp*8]);
        }
#pragma unroll
        for (int m = 0; m < 4; m++) {
            acc[m][0] = __builtin_amdgcn_mfma_f32_16x16x32_bf16(a[m], Bf[0][k], acc[m][0], 0, 0, 0);
            acc[m][1] = __builtin_amdgcn_mfma_f32_16x16x32_bf16(a[m], Bf[1][k], acc[m][1], 0, 0, 0);
        }
    }

    // ---- epilogue: C/D layout col=li, row=quad*4+reg (m89-verified)
    float Ssum = 0.f, oa0 = 0.f, oa1 = 0.f;
#pragma unroll
    for (int m = 0; m < 4; m++) {
#pragma unroll
        for (int r = 0; r < 4; r++) {
            float x0 = acc[m][0][r] + bl0;
            float x1 = acc[m][1][r] + bl1;
            float e0 = x0 + xr0; e0 = e0 > 0.f ? e0 : 0.2f*e0;
            float e1 = x1 + xr1; e1 = e1 > 0.f ? e1 : 0.2f*e1;
            float p = qsum16(at0*e0 + at1*e1);   // row logit, uniform in quad
            float w = __expf(fminf(p, 60.f));
            Ssum += w;
            oa0 += w * x0;
            oa1 += w * x1;
        }
    }

    // combine quads (disjoint rows; li is the column)
    Ssum += __shfl_xor(Ssum, 16); Ssum += __shfl_xor(Ssum, 32);
    oa0  += __shfl_xor(oa0, 16);  oa0  += __shfl_xor(oa0, 32);
    oa1  += __shfl_xor(oa1, 16);  oa1  += __shfl_xor(oa1, 32);

    if (lane == 0) atomicAdd(&accR[wave], Ssum);
    if (lane < 16) {
        atomicAdd(&accR[8 + wave*32 + lane],      oa0);
        atomicAdd(&accR[8 + wave*32 + 16 + lane], oa1);
    }
}

// ---------------------------------------------------------------------------
// Merge buckets: out_gat = O/S + bias; x = prev + out_gat; LN+relu -> xn.
// ---------------------------------------------------------------------------
template<bool F32>
__global__ __launch_bounds__(512)
void combine_k(const float* __restrict__ accSO,
               const void* __restrict__ prev,
               const void* __restrict__ v_bias, const void* __restrict__ s_bias,
               const void* __restrict__ pre_s, const void* __restrict__ pre_b,
               const void* __restrict__ det,
               float* __restrict__ x_skip, float* __restrict__ xn)
{
    if (is_bf16(det) == F32) return;
    const int t = threadIdx.x;
    const int branch = t >> 8, c = t & 255, h = c >> 5;
    float S = 0.f, o = 0.f;
#pragma unroll
    for (int b = 0; b < NBUCK; b++) {
        S += accSO[b*528 + branch*264 + h];
        o += accSO[b*528 + branch*264 + 8 + c];
    }
    const void* bias = branch ? s_bias : v_bias;
    float xv = ldT<F32>(prev, t) + o / S + ldT<F32>(bias, c);
    x_skip[t] = xv;
    __shared__ float red[16];
    __shared__ float stats[2];
    float s1 = xv, s2 = xv*xv;
#pragma unroll
    for (int s = 1; s < 64; s <<= 1) { s1 += __shfl_xor(s1, s); s2 += __shfl_xor(s2, s); }
    if ((t & 63) == 0) { red[t >> 6] = s1; red[8 + (t >> 6)] = s2; }
    __syncthreads();
    if (t == 0) {
        float a = 0.f, q = 0.f;
        for (int i = 0; i < 8; i++) { a += red[i]; q += red[8 + i]; }
        float mean = a / 512.f;
        stats[0] = mean;
        stats[1] = rsqrtf(q / 512.f - mean*mean + 1e-5f);
    }
    __syncthreads();
    float xnv = (xv - stats[0]) * stats[1] * ldT<F32>(pre_s, t) + ldT<F32>(pre_b, t);
    xn[t] = fmaxf(xnv, 0.f);
}

// ---------------------------------------------------------------------------
// out = x_skip + xn @ mlp_W + mlp_b.  8 blocks x 64 cols, K-split x4, batch 32.
// ---------------------------------------------------------------------------
template<bool F32>
__global__ __launch_bounds__(256)
void mlp_k(const float* __restrict__ x_skip, const float* __restrict__ xn,
           const void* __restrict__ W, const void* __restrict__ mb,
           const void* __restrict__ det,
           void* __restrict__ out)
{
    if (is_bf16(det) == F32) return;
    __shared__ float xs[512];
    __shared__ float part[256];
    const int t = threadIdx.x;
    for (int i = t; i < 512; i += 256) xs[i] = xn[i];
    __syncthreads();
    const int c  = blockIdx.x*64 + (t & 63);
    const int kh = t >> 6;               // 0..3, 128 K each
    const int b  = kh * 128;
    float acc = 0.f;
    for (int ii = 0; ii < 128; ii += 32) {
        float wv[32];
#pragma unroll
        for (int u = 0; u < 32; u++) wv[u] = ldT<F32>(W, (b + ii + u)*512 + c);
#pragma unroll
        for (int u = 0; u < 32; u++) acc += xs[b + ii + u] * wv[u];
    }
    part[t] = acc;
    __syncthreads();
    if (t < 64) {
        float r = x_skip[c] + part[t] + part[t + 64] + part[t + 128] + part[t + 192]
                + ldT<F32>(mb, c);
        if (F32) ((float*)out)[c] = r;
        else     ((ushort_t*)out)[c] = f2bf(r);
    }
}

extern "C" void kernel_launch(void* const* d_in, const int* in_sizes, int n_in,
                              void* d_out, int out_size, void* d_ws, size_t ws_size,
                              hipStream_t stream)
{
    const void* view_x  = d_in[0];
    const void* scene_x = d_in[1];
    const void* prev    = d_in[2];
    const void* g2v_lns = d_in[3];   // ones(512) -> dtype detector
    const void* g2v_lnb = d_in[4];
    const void* g2v_W   = d_in[5];
    const void* g2v_b   = d_in[6];
    const void* g2s_lns = d_in[7];
    const void* g2s_lnb = d_in[8];
    const void* g2s_W   = d_in[9];
    const void* g2s_b   = d_in[10];
    const void* v_Wl    = d_in[11];
    const void* v_bl    = d_in[12];
    const void* v_Wr    = d_in[13];
    const void* v_br    = d_in[14];
    const void* v_att   = d_in[15];
    const void* v_bias  = d_in[16];
    const void* s_Wl    = d_in[17];
    const void* s_bl    = d_in[18];
    const void* s_Wr    = d_in[19];
    const void* s_br    = d_in[20];
    const void* s_att   = d_in[21];
    const void* s_bias  = d_in[22];
    const void* pre_s   = d_in[23];
    const void* pre_b   = d_in[24];
    const void* mlp_W   = d_in[25];
    const void* mlp_b   = d_in[26];

    float* wsf    = (float*)d_ws;
    float* xr     = wsf + WS_XR;
    float* accSO  = wsf + WS_ACC;
    float* x_skip = wsf + WS_SKIP;
    float* xn     = wsf + WS_XN;

    prep_k<false><<<dim3(2), dim3(512), 0, stream>>>(prev,
                                              g2v_lns, g2v_lnb, g2v_W, g2v_b, v_Wr, v_br,
                                              g2s_lns, g2s_lnb, g2s_W, g2s_b, s_Wr, s_br,
                                              xr, accSO);
    prep_k<true><<<dim3(2), dim3(512), 0, stream>>>(prev,
                                              g2v_lns, g2v_lnb, g2v_W, g2v_b, v_Wr, v_br,
                                              g2s_lns, g2s_lnb, g2s_W, g2s_b, s_Wr, s_br,
                                              xr, accSO);
    gat_k<false><<<dim3(NSCENE + NVIEW), dim3(512), 0, stream>>>(view_x, scene_x, v_Wl, s_Wl,
                                                                 xr, v_bl, s_bl, v_att, s_att,
                                                                 g2v_lns, accSO);
    gat_k<true><<<dim3(NSCENE + NVIEW), dim3(512), 0, stream>>>(view_x, scene_x, v_Wl, s_Wl,
                                                                xr, v_bl, s_bl, v_att, s_att,
                                                                g2v_lns, accSO);
    combine_k<false><<<dim3(1), dim3(512), 0, stream>>>(accSO, prev, v_bias, s_bias,
                                                        pre_s, pre_b, g2v_lns, x_skip, xn);
    combine_k<true><<<dim3(1), dim3(512), 0, stream>>>(accSO, prev, v_bias, s_bias,
                                                       pre_s, pre_b, g2v_lns, x_skip, xn);
    mlp_k<false><<<dim3(8), dim3(256), 0, stream>>>(x_skip, xn, mlp_W, mlp_b, g2v_lns, d_out);
    mlp_k<true><<<dim3(8), dim3(256), 0, stream>>>(x_skip, xn, mlp_W, mlp_b, g2v_lns, d_out);
}